// Round 1
// baseline (521.376 us; speedup 1.0000x reference)
//
#include <hip/hip_runtime.h>
#include <hip/hip_bf16.h>

typedef __attribute__((ext_vector_type(8))) short bf16x8;
typedef __attribute__((ext_vector_type(8))) unsigned short ushort8;
typedef __attribute__((ext_vector_type(4))) float f32x4;

#define MFMA16(a, b, c) __builtin_amdgcn_mfma_f32_16x16x32_bf16(a, b, c, 0, 0, 0)

__device__ __forceinline__ unsigned short f2bf(float x) {
    unsigned u = __builtin_bit_cast(unsigned, x);
    u += 0x7FFFu + ((u >> 16) & 1u);
    return (unsigned short)(u >> 16);
}

__device__ __forceinline__ void gload16(const void* g, void* l) {
    __builtin_amdgcn_global_load_lds((const __attribute__((address_space(1))) void*)g,
                                     (__attribute__((address_space(3))) void*)l, 16, 0, 0);
}

// ---------------- fp32 -> bf16 conversion (8 elems/thread/iter) ----------------
__global__ void cvt_f32_bf16(const float* __restrict__ src, unsigned short* __restrict__ dst, int n8) {
    int stride = gridDim.x * blockDim.x;
    for (int i = blockIdx.x * blockDim.x + threadIdx.x; i < n8; i += stride) {
        const float4* s = reinterpret_cast<const float4*>(src) + (size_t)i * 2;
        float4 a = s[0], b = s[1];
        ushort8 o;
        o[0] = f2bf(a.x); o[1] = f2bf(a.y); o[2] = f2bf(a.z); o[3] = f2bf(a.w);
        o[4] = f2bf(b.x); o[5] = f2bf(b.y); o[6] = f2bf(b.z); o[7] = f2bf(b.w);
        *(reinterpret_cast<ushort8*>(dst) + i) = o;
    }
}

// ---------------- bf16 GEMM, C = A @ B^T  (A:[M,K], B:[N,K] row-major) --------
// m97 structure: 128x128 tile, BK=64, 4 waves (2x2), global_load_lds width 16.
template <int STORE_F32>
__global__ __launch_bounds__(256, 2)
void gemm_bt(const unsigned short* __restrict__ A, const unsigned short* __restrict__ B,
             void* __restrict__ C, int M, int N, int K) {
    __shared__ unsigned short As[128 * 64];
    __shared__ unsigned short Bs[128 * 64];
    const int tid  = threadIdx.x;
    const int wid  = tid >> 6;
    const int lane = tid & 63;
    const int wr   = wid >> 1, wc = wid & 1;
    const int lrow = lane >> 4, lcol = lane & 15;
    const int bm = blockIdx.y, bn = blockIdx.x;

    const int srow = tid >> 3;          // 0..31
    const int scol = (tid & 7) * 8;     // 0..56
    const unsigned short* aptr = A + (size_t)(bm * 128 + srow) * K + scol;
    const unsigned short* bptr = B + (size_t)(bn * 128 + srow) * K + scol;
    char* asb = (char*)As + wid * 1024;
    char* bsb = (char*)Bs + wid * 1024;

    f32x4 acc[4][4] = {};

    for (int k0 = 0; k0 < K; k0 += 64) {
#pragma unroll
        for (int q = 0; q < 4; ++q) {
            gload16(aptr + (size_t)q * 32 * K + k0, asb + q * 4096);
            gload16(bptr + (size_t)q * 32 * K + k0, bsb + q * 4096);
        }
        asm volatile("s_waitcnt vmcnt(0)" ::: "memory");
        __syncthreads();
#pragma unroll
        for (int kk = 0; kk < 2; ++kk) {
            bf16x8 af[4], bfr[4];
#pragma unroll
            for (int m = 0; m < 4; ++m)
                af[m] = *reinterpret_cast<const bf16x8*>(&As[(wr * 64 + m * 16 + lcol) * 64 + kk * 32 + lrow * 8]);
#pragma unroll
            for (int n = 0; n < 4; ++n)
                bfr[n] = *reinterpret_cast<const bf16x8*>(&Bs[(wc * 64 + n * 16 + lcol) * 64 + kk * 32 + lrow * 8]);
#pragma unroll
            for (int m = 0; m < 4; ++m)
#pragma unroll
                for (int n = 0; n < 4; ++n)
                    acc[m][n] = MFMA16(af[m], bfr[n], acc[m][n]);
        }
        __syncthreads();
    }

    const int row0 = bm * 128 + wr * 64;
    const int col0 = bn * 128 + wc * 64;
#pragma unroll
    for (int m = 0; m < 4; ++m)
#pragma unroll
        for (int n = 0; n < 4; ++n)
#pragma unroll
            for (int r = 0; r < 4; ++r) {
                int row = row0 + m * 16 + lrow * 4 + r;
                int col = col0 + n * 16 + lcol;
                if (STORE_F32)
                    ((float*)C)[(size_t)row * N + col] = acc[m][n][r];
                else
                    ((unsigned short*)C)[(size_t)row * N + col] = f2bf(acc[m][n][r]);
            }
}

// ---------------- sliding-window attention ------------------------------------
// grid (nb=32, H=32, B=2), 256 threads. Wave w owns query rows i*128+w*32 .. +31.
// Online softmax over the 2 key chunks (each 128 keys). dk = 64.
__global__ __launch_bounds__(256, 2)
void swa_attn(const unsigned short* __restrict__ Qb, const unsigned short* __restrict__ Kb,
              const unsigned short* __restrict__ Vb, unsigned short* __restrict__ Ob) {
    constexpr int T = 4096, D = 2048, BS = 128;
    __shared__ unsigned short vt[64][136];       // V^T chunk: [d][k]
    __shared__ unsigned short pl[4][32][136];    // per-wave P: [qrow][k]

    const int i = blockIdx.x, h = blockIdx.y, b = blockIdx.z;
    const int tid = threadIdx.x;
    const int wid = tid >> 6, lane = tid & 63;
    const int lrow = lane >> 4, lcol = lane & 15;

    const size_t hoff = (size_t)h * 64;
    const unsigned short* qbase = Qb + (size_t)b * T * D + hoff;
    const unsigned short* kbase = Kb + (size_t)b * T * D + hoff;
    const unsigned short* vbase = Vb + (size_t)b * T * D + hoff;

    const int qr0 = i * BS + wid * 32;
    bf16x8 aq[2][2];
#pragma unroll
    for (int m = 0; m < 2; ++m)
#pragma unroll
        for (int kf = 0; kf < 2; ++kf)
            aq[m][kf] = *reinterpret_cast<const bf16x8*>(
                qbase + (size_t)(qr0 + m * 16 + lcol) * D + kf * 32 + lrow * 8);

    f32x4 oacc[2][4] = {};
    float mrun[2][4], lrun[2][4];
#pragma unroll
    for (int m = 0; m < 2; ++m)
#pragma unroll
        for (int r = 0; r < 4; ++r) { mrun[m][r] = -1e30f; lrun[m][r] = 0.f; }

    const int t0 = (i == 0) ? 1 : 0;
    for (int t = t0; t < 2; ++t) {
        const int kt0 = (i - 1) * BS + t * BS;   // first key token of chunk

        // stage V^T (coalesced 16B global loads, scattered b16 LDS writes)
#pragma unroll
        for (int it = 0; it < 4; ++it) {
            int e = it * 2048 + tid * 8;
            int kr = e >> 6;
            int dc = e & 63;
            bf16x8 v = *reinterpret_cast<const bf16x8*>(vbase + (size_t)(kt0 + kr) * D + dc);
#pragma unroll
            for (int j = 0; j < 8; ++j) vt[dc + j][kr] = (unsigned short)v[j];
        }

        // S = Q K^T  (K fragments straight from global)
        f32x4 s[2][8];
#pragma unroll
        for (int n = 0; n < 8; ++n) {
            const int ktr = kt0 + n * 16 + lcol;
            bf16x8 bk0 = *reinterpret_cast<const bf16x8*>(kbase + (size_t)ktr * D + lrow * 8);
            bf16x8 bk1 = *reinterpret_cast<const bf16x8*>(kbase + (size_t)ktr * D + 32 + lrow * 8);
#pragma unroll
            for (int m = 0; m < 2; ++m) {
                f32x4 a = {0.f, 0.f, 0.f, 0.f};
                a = MFMA16(aq[m][0], bk0, a);
                a = MFMA16(aq[m][1], bk1, a);
                s[m][n] = a;
            }
        }

        // scale + banded causal mask. window col c valid iff r <= c <= r+128.
#pragma unroll
        for (int m = 0; m < 2; ++m)
#pragma unroll
            for (int n = 0; n < 8; ++n)
#pragma unroll
                for (int r = 0; r < 4; ++r) {
                    int qr = wid * 32 + m * 16 + lrow * 4 + r;
                    int c  = t * BS + n * 16 + lcol;
                    bool valid = (c >= qr) && (c <= qr + BS);
                    s[m][n][r] = valid ? s[m][n][r] * 0.125f : -1e30f;
                }

        // online softmax (row stats live in the 16 lanes of each lcol group)
#pragma unroll
        for (int m = 0; m < 2; ++m)
#pragma unroll
            for (int r = 0; r < 4; ++r) {
                float cm = s[m][0][r];
#pragma unroll
                for (int n = 1; n < 8; ++n) cm = fmaxf(cm, s[m][n][r]);
                cm = fmaxf(cm, __shfl_xor(cm, 1));
                cm = fmaxf(cm, __shfl_xor(cm, 2));
                cm = fmaxf(cm, __shfl_xor(cm, 4));
                cm = fmaxf(cm, __shfl_xor(cm, 8));
                float mnew = fmaxf(mrun[m][r], cm);
                float sf = __expf(mrun[m][r] - mnew);
                float rs = 0.f;
#pragma unroll
                for (int n = 0; n < 8; ++n) {
                    float p = __expf(s[m][n][r] - mnew);
                    s[m][n][r] = p;
                    rs += p;
                }
                rs += __shfl_xor(rs, 1);
                rs += __shfl_xor(rs, 2);
                rs += __shfl_xor(rs, 4);
                rs += __shfl_xor(rs, 8);
                lrun[m][r] = lrun[m][r] * sf + rs;
                mrun[m][r] = mnew;
#pragma unroll
                for (int nf = 0; nf < 4; ++nf) oacc[m][nf][r] *= sf;
            }

        // P -> LDS (bf16), per-wave region
#pragma unroll
        for (int m = 0; m < 2; ++m)
#pragma unroll
            for (int n = 0; n < 8; ++n)
#pragma unroll
                for (int r = 0; r < 4; ++r)
                    pl[wid][m * 16 + lrow * 4 + r][n * 16 + lcol] = f2bf(s[m][n][r]);

        __syncthreads();   // vt visible to all waves; own P writes drained

        // O += P @ V  (A = P from pl, B = V via vt, all ds_read_b128)
#pragma unroll
        for (int kf2 = 0; kf2 < 4; ++kf2) {
            bf16x8 ap0 = *reinterpret_cast<const bf16x8*>(&pl[wid][lcol][kf2 * 32 + lrow * 8]);
            bf16x8 ap1 = *reinterpret_cast<const bf16x8*>(&pl[wid][16 + lcol][kf2 * 32 + lrow * 8]);
#pragma unroll
            for (int nf = 0; nf < 4; ++nf) {
                bf16x8 bv = *reinterpret_cast<const bf16x8*>(&vt[nf * 16 + lcol][kf2 * 32 + lrow * 8]);
                oacc[0][nf] = MFMA16(ap0, bv, oacc[0][nf]);
                oacc[1][nf] = MFMA16(ap1, bv, oacc[1][nf]);
            }
        }
        __syncthreads();   // PV reads done before next chunk restages vt
    }

    // normalize + store bf16 [B,T,H*dk]
#pragma unroll
    for (int m = 0; m < 2; ++m)
#pragma unroll
        for (int r = 0; r < 4; ++r) {
            float inv = 1.f / lrun[m][r];
            int tok = i * BS + wid * 32 + m * 16 + lrow * 4 + r;
            unsigned short* orow = Ob + (size_t)(b * T + tok) * D + hoff;
#pragma unroll
            for (int nf = 0; nf < 4; ++nf)
                orow[nf * 16 + lcol] = f2bf(oacc[m][nf][r] * inv);
        }
}

// ---------------- launch -------------------------------------------------------
extern "C" void kernel_launch(void* const* d_in, const int* in_sizes, int n_in,
                              void* d_out, int out_size, void* d_ws, size_t ws_size,
                              hipStream_t stream) {
    const float* x  = (const float*)d_in[0];
    const float* Wq = (const float*)d_in[1];
    const float* Wk = (const float*)d_in[2];
    const float* Wv = (const float*)d_in[3];
    const float* Wo = (const float*)d_in[4];

    constexpr int B = 2, T = 4096, D = 2048;
    constexpr int M = B * T;                    // 8192
    constexpr size_t XE = (size_t)M * D;        // 16,777,216 elems
    constexpr size_t WE = (size_t)D * D;        // 4,194,304 elems

    char* ws = (char*)d_ws;
    unsigned short* xb  = (unsigned short*)(ws);
    unsigned short* wqb = (unsigned short*)(ws + XE * 2);
    unsigned short* wkb = (unsigned short*)(ws + XE * 2 + WE * 2);
    unsigned short* wvb = (unsigned short*)(ws + XE * 2 + WE * 4);
    unsigned short* wob = (unsigned short*)(ws + XE * 2 + WE * 6);
    unsigned short* qb  = (unsigned short*)(ws + XE * 2 + WE * 8);
    unsigned short* kb  = (unsigned short*)(ws + XE * 4 + WE * 8);
    unsigned short* vb  = (unsigned short*)(ws + XE * 6 + WE * 8);
    unsigned short* ab  = (unsigned short*)(ws + XE * 8 + WE * 8);

    cvt_f32_bf16<<<2048, 256, 0, stream>>>(x,  xb,  (int)(XE / 8));
    cvt_f32_bf16<<<2048, 256, 0, stream>>>(Wq, wqb, (int)(WE / 8));
    cvt_f32_bf16<<<2048, 256, 0, stream>>>(Wk, wkb, (int)(WE / 8));
    cvt_f32_bf16<<<2048, 256, 0, stream>>>(Wv, wvb, (int)(WE / 8));
    cvt_f32_bf16<<<2048, 256, 0, stream>>>(Wo, wob, (int)(WE / 8));

    dim3 gg(D / 128, M / 128);   // (16, 64)
    gemm_bt<0><<<gg, 256, 0, stream>>>(xb, wqb, qb, M, D, D);
    gemm_bt<0><<<gg, 256, 0, stream>>>(xb, wkb, kb, M, D, D);
    gemm_bt<0><<<gg, 256, 0, stream>>>(xb, wvb, vb, M, D, D);

    swa_attn<<<dim3(32, 32, 2), 256, 0, stream>>>(qb, kb, vb, ab);

    gemm_bt<1><<<gg, 256, 0, stream>>>(ab, wob, d_out, M, D, D);
}

// Round 2
// 377.021 us; speedup vs baseline: 1.3829x; 1.3829x over previous
//
#include <hip/hip_runtime.h>
#include <hip/hip_bf16.h>

typedef __attribute__((ext_vector_type(8))) short bf16x8;
typedef __attribute__((ext_vector_type(8))) unsigned short ushort8;
typedef __attribute__((ext_vector_type(4))) float f32x4;

#define MFMA16(a, b, c) __builtin_amdgcn_mfma_f32_16x16x32_bf16(a, b, c, 0, 0, 0)

__device__ __forceinline__ unsigned short f2bf(float x) {
    unsigned u = __builtin_bit_cast(unsigned, x);
    u += 0x7FFFu + ((u >> 16) & 1u);
    return (unsigned short)(u >> 16);
}

__device__ __forceinline__ void gload16(const void* g, void* l) {
    __builtin_amdgcn_global_load_lds((const __attribute__((address_space(1))) void*)g,
                                     (__attribute__((address_space(3))) void*)l, 16, 0, 0);
}

__device__ __forceinline__ void bar() {
    asm volatile("" ::: "memory");
    __builtin_amdgcn_s_barrier();
    asm volatile("" ::: "memory");
}

#define WAITL() do { asm volatile("s_waitcnt lgkmcnt(0)" ::: "memory"); \
                     __builtin_amdgcn_sched_barrier(0); } while (0)

// ---------------- fp32 -> bf16 conversion (8 elems/thread/iter) ----------------
__global__ void cvt_f32_bf16(const float* __restrict__ src, unsigned short* __restrict__ dst, int n8) {
    int stride = gridDim.x * blockDim.x;
    for (int i = blockIdx.x * blockDim.x + threadIdx.x; i < n8; i += stride) {
        const float4* s = reinterpret_cast<const float4*>(src) + (size_t)i * 2;
        float4 a = s[0], b = s[1];
        ushort8 o;
        o[0] = f2bf(a.x); o[1] = f2bf(a.y); o[2] = f2bf(a.z); o[3] = f2bf(a.w);
        o[4] = f2bf(b.x); o[5] = f2bf(b.y); o[6] = f2bf(b.z); o[7] = f2bf(b.w);
        *(reinterpret_cast<ushort8*>(dst) + i) = o;
    }
}

// ---------------- 256x256 8-phase bf16 GEMM, C = A @ B^T ----------------------
// A:[M,K], B:[N,K] row-major. 512 threads = 8 waves (2 wr x 4 wc), interleaved
// fragments: wave owns rows {m*32+wr*16}, cols {n*64+wc*16}. BK=64, double-buffered
// 128 KiB LDS, halves staged one-per-phase via global_load_lds, counted vmcnt(6).
// XOR swizzle slot^=(row&7) on pre-swizzled global source + swizzled ds_read.
#define QUAD(mg, ng, bfv)                                                         \
    do {                                                                          \
        _Pragma("unroll") for (int mm = 0; mm < 4; ++mm)                          \
        _Pragma("unroll") for (int nn = 0; nn < 2; ++nn)                          \
        _Pragma("unroll") for (int kk = 0; kk < 2; ++kk)                          \
            acc[(mg) * 4 + mm][(ng) * 2 + nn] =                                   \
                MFMA16(af[mm][kk], bfv[nn][kk], acc[(mg) * 4 + mm][(ng) * 2 + nn]); \
    } while (0)

template <int STORE_F32>
__global__ __launch_bounds__(512, 2)
void gemm256(const unsigned short* __restrict__ A, const unsigned short* __restrict__ B,
             void* __restrict__ C, int M, int N, int K) {
    __shared__ char sm[131072];   // A: [0,64K) = d*32K + h*16K ; B: [64K,128K)

    const int tid  = threadIdx.x;
    const int wid  = tid >> 6, lane = tid & 63;
    const int wr   = wid >> 2, wc = wid & 3;
    const int lrow = lane >> 4, lcol = lane & 15;

    // bijective XCD swizzle (gridDim.x % 8 == 0)
    const int flat = blockIdx.x;
    const int s = (flat & 7) * (gridDim.x >> 3) + (flat >> 3);
    const int nbn = N >> 8;
    const int bm = s / nbn, bn = s % nbn;

    // staging: thread -> (row, slot) of a 128x64 half-tile; source pre-swizzled
    const int srow = wid * 8 + (lane >> 3);                      // 0..63 (+q*64)
    const int scol = ((lane & 7) ^ ((lane >> 3) & 7)) * 8;       // element col
    const unsigned short* aS = A + (size_t)(bm * 256 + srow) * K + scol;
    const unsigned short* bS = B + (size_t)(bn * 256 + srow) * K + scol;
    const int ldsW = wid * 1024;

    auto stageA = [&](int d, int h, int t) {
#pragma unroll
        for (int q = 0; q < 2; ++q)
            gload16(aS + (size_t)(h * 128 + q * 64) * K + t * 64,
                    sm + d * 32768 + h * 16384 + ldsW + q * 8192);
    };
    auto stageB = [&](int d, int h, int t) {
#pragma unroll
        for (int q = 0; q < 2; ++q)
            gload16(bS + (size_t)(h * 128 + q * 64) * K + t * 64,
                    sm + 65536 + d * 32768 + h * 16384 + ldsW + q * 8192);
    };

    // ds_read fragment addressing (swizzled)
    const int swz0 = (lrow * 16) ^ ((lcol & 7) << 4);
    const int swz1 = (64 + lrow * 16) ^ ((lcol & 7) << 4);
    const int ra = wr * 16 + lcol;
    const int rb = wc * 16 + lcol;

    bf16x8 af[4][2], bl[2][2], bh[2][2];
    auto loadA = [&](int d, int mg) {
#pragma unroll
        for (int mm = 0; mm < 4; ++mm) {
            af[mm][0] = *(const bf16x8*)(sm + d * 32768 + mg * 16384 + (mm * 32 + ra) * 128 + swz0);
            af[mm][1] = *(const bf16x8*)(sm + d * 32768 + mg * 16384 + (mm * 32 + ra) * 128 + swz1);
        }
    };
    auto loadB = [&](int d, int ng, bf16x8 (&bfv)[2][2]) {
#pragma unroll
        for (int nn = 0; nn < 2; ++nn) {
            bfv[nn][0] = *(const bf16x8*)(sm + 65536 + d * 32768 + ng * 16384 + (nn * 64 + rb) * 128 + swz0);
            bfv[nn][1] = *(const bf16x8*)(sm + 65536 + d * 32768 + ng * 16384 + (nn * 64 + rb) * 128 + swz1);
        }
    };

    f32x4 acc[8][4] = {};

    // prologue: stage tile0 fully + 3 halves of tile1 (issue order matters for vmcnt)
    stageA(0, 0, 0); stageB(0, 0, 0); stageB(0, 1, 0); stageA(0, 1, 0);
    stageA(1, 0, 1); stageB(1, 0, 1); stageB(1, 1, 1);
    asm volatile("s_waitcnt vmcnt(6)" ::: "memory");
    bar();

    const int NI = K / 128;   // 2 K-tiles per iteration
#pragma unroll 1
    for (int i = 0; i < NI; ++i) {
        const int t0 = 2 * i;
        const bool last = (i == NI - 1);
        // ---- P0: tile t0 (buf0), quadrant m-low x n-low ----
        loadA(0, 0); loadB(0, 0, bl);
        stageA(1, 1, t0 + 1);
        bar(); WAITL();
        __builtin_amdgcn_s_setprio(1); QUAD(0, 0, bl); __builtin_amdgcn_s_setprio(0);
        bar();
        // ---- P1: m-low x n-high ----
        loadB(0, 1, bh);
        if (!last) stageA(0, 0, t0 + 2);
        bar(); WAITL();
        __builtin_amdgcn_s_setprio(1); QUAD(0, 1, bh); __builtin_amdgcn_s_setprio(0);
        bar();
        // ---- P2: m-high x n-low ----
        loadA(0, 1);
        if (!last) stageB(0, 0, t0 + 2);
        bar(); WAITL();
        __builtin_amdgcn_s_setprio(1); QUAD(1, 0, bl); __builtin_amdgcn_s_setprio(0);
        bar();
        // ---- P3: m-high x n-high; vmcnt gate for buf1 reads ----
        if (!last) stageB(0, 1, t0 + 2);
        bar();
        __builtin_amdgcn_s_setprio(1); QUAD(1, 1, bh); __builtin_amdgcn_s_setprio(0);
        if (last) asm volatile("s_waitcnt vmcnt(0)" ::: "memory");
        else      asm volatile("s_waitcnt vmcnt(6)" ::: "memory");
        bar();
        // ---- P4: tile t0+1 (buf1), m-low x n-low ----
        loadA(1, 0); loadB(1, 0, bl);
        if (!last) stageA(0, 1, t0 + 2);
        bar(); WAITL();
        __builtin_amdgcn_s_setprio(1); QUAD(0, 0, bl); __builtin_amdgcn_s_setprio(0);
        bar();
        // ---- P5 ----
        loadB(1, 1, bh);
        if (!last) stageA(1, 0, t0 + 3);
        bar(); WAITL();
        __builtin_amdgcn_s_setprio(1); QUAD(0, 1, bh); __builtin_amdgcn_s_setprio(0);
        bar();
        // ---- P6 ----
        loadA(1, 1);
        if (!last) stageB(1, 0, t0 + 3);
        bar(); WAITL();
        __builtin_amdgcn_s_setprio(1); QUAD(1, 0, bl); __builtin_amdgcn_s_setprio(0);
        bar();
        // ---- P7: vmcnt gate for next iter's buf0 reads ----
        if (!last) stageB(1, 1, t0 + 3);
        bar();
        __builtin_amdgcn_s_setprio(1); QUAD(1, 1, bh); __builtin_amdgcn_s_setprio(0);
        if (!last) asm volatile("s_waitcnt vmcnt(6)" ::: "memory");
        bar();
    }

    // epilogue: C[row, col], row = bm*256 + m*32 + wr*16 + lrow*4 + r
    const size_t row0 = (size_t)bm * 256 + wr * 16 + lrow * 4;
    const int col0 = bn * 256 + wc * 16 + lcol;
#pragma unroll
    for (int m = 0; m < 8; ++m)
#pragma unroll
        for (int n = 0; n < 4; ++n)
#pragma unroll
            for (int r = 0; r < 4; ++r) {
                size_t row = row0 + m * 32 + r;
                size_t col = (size_t)col0 + n * 64;
                if (STORE_F32)
                    ((float*)C)[row * N + col] = acc[m][n][r];
                else
                    ((unsigned short*)C)[row * N + col] = f2bf(acc[m][n][r]);
            }
}

// ---------------- sliding-window attention ------------------------------------
__global__ __launch_bounds__(256, 2)
void swa_attn(const unsigned short* __restrict__ Qb, const unsigned short* __restrict__ Kb,
              const unsigned short* __restrict__ Vb, unsigned short* __restrict__ Ob) {
    constexpr int T = 4096, D = 2048, BS = 128;
    __shared__ unsigned short vt[64][136];       // V^T chunk: [d][k]
    __shared__ unsigned short pl[4][32][136];    // per-wave P: [qrow][k]

    const int i = blockIdx.x, h = blockIdx.y, b = blockIdx.z;
    const int tid = threadIdx.x;
    const int wid = tid >> 6, lane = tid & 63;
    const int lrow = lane >> 4, lcol = lane & 15;

    const size_t hoff = (size_t)h * 64;
    const unsigned short* qbase = Qb + (size_t)b * T * D + hoff;
    const unsigned short* kbase = Kb + (size_t)b * T * D + hoff;
    const unsigned short* vbase = Vb + (size_t)b * T * D + hoff;

    const int qr0 = i * BS + wid * 32;
    bf16x8 aq[2][2];
#pragma unroll
    for (int m = 0; m < 2; ++m)
#pragma unroll
        for (int kf = 0; kf < 2; ++kf)
            aq[m][kf] = *reinterpret_cast<const bf16x8*>(
                qbase + (size_t)(qr0 + m * 16 + lcol) * D + kf * 32 + lrow * 8);

    f32x4 oacc[2][4] = {};
    float mrun[2][4], lrun[2][4];
#pragma unroll
    for (int m = 0; m < 2; ++m)
#pragma unroll
        for (int r = 0; r < 4; ++r) { mrun[m][r] = -1e30f; lrun[m][r] = 0.f; }

    const int t0 = (i == 0) ? 1 : 0;
    for (int t = t0; t < 2; ++t) {
        const int kt0 = (i - 1) * BS + t * BS;

#pragma unroll
        for (int it = 0; it < 4; ++it) {
            int e = it * 2048 + tid * 8;
            int kr = e >> 6;
            int dc = e & 63;
            bf16x8 v = *reinterpret_cast<const bf16x8*>(vbase + (size_t)(kt0 + kr) * D + dc);
#pragma unroll
            for (int j = 0; j < 8; ++j) vt[dc + j][kr] = (unsigned short)v[j];
        }

        f32x4 s[2][8];
#pragma unroll
        for (int n = 0; n < 8; ++n) {
            const int ktr = kt0 + n * 16 + lcol;
            bf16x8 bk0 = *reinterpret_cast<const bf16x8*>(kbase + (size_t)ktr * D + lrow * 8);
            bf16x8 bk1 = *reinterpret_cast<const bf16x8*>(kbase + (size_t)ktr * D + 32 + lrow * 8);
#pragma unroll
            for (int m = 0; m < 2; ++m) {
                f32x4 a = {0.f, 0.f, 0.f, 0.f};
                a = MFMA16(aq[m][0], bk0, a);
                a = MFMA16(aq[m][1], bk1, a);
                s[m][n] = a;
            }
        }

#pragma unroll
        for (int m = 0; m < 2; ++m)
#pragma unroll
            for (int n = 0; n < 8; ++n)
#pragma unroll
                for (int r = 0; r < 4; ++r) {
                    int qr = wid * 32 + m * 16 + lrow * 4 + r;
                    int c  = t * BS + n * 16 + lcol;
                    bool valid = (c >= qr) && (c <= qr + BS);
                    s[m][n][r] = valid ? s[m][n][r] * 0.125f : -1e30f;
                }

#pragma unroll
        for (int m = 0; m < 2; ++m)
#pragma unroll
            for (int r = 0; r < 4; ++r) {
                float cm = s[m][0][r];
#pragma unroll
                for (int n = 1; n < 8; ++n) cm = fmaxf(cm, s[m][n][r]);
                cm = fmaxf(cm, __shfl_xor(cm, 1));
                cm = fmaxf(cm, __shfl_xor(cm, 2));
                cm = fmaxf(cm, __shfl_xor(cm, 4));
                cm = fmaxf(cm, __shfl_xor(cm, 8));
                float mnew = fmaxf(mrun[m][r], cm);
                float sf = __expf(mrun[m][r] - mnew);
                float rs = 0.f;
#pragma unroll
                for (int n = 0; n < 8; ++n) {
                    float p = __expf(s[m][n][r] - mnew);
                    s[m][n][r] = p;
                    rs += p;
                }
                rs += __shfl_xor(rs, 1);
                rs += __shfl_xor(rs, 2);
                rs += __shfl_xor(rs, 4);
                rs += __shfl_xor(rs, 8);
                lrun[m][r] = lrun[m][r] * sf + rs;
                mrun[m][r] = mnew;
#pragma unroll
                for (int nf = 0; nf < 4; ++nf) oacc[m][nf][r] *= sf;
            }

#pragma unroll
        for (int m = 0; m < 2; ++m)
#pragma unroll
            for (int n = 0; n < 8; ++n)
#pragma unroll
                for (int r = 0; r < 4; ++r)
                    pl[wid][m * 16 + lrow * 4 + r][n * 16 + lcol] = f2bf(s[m][n][r]);

        __syncthreads();

#pragma unroll
        for (int kf2 = 0; kf2 < 4; ++kf2) {
            bf16x8 ap0 = *reinterpret_cast<const bf16x8*>(&pl[wid][lcol][kf2 * 32 + lrow * 8]);
            bf16x8 ap1 = *reinterpret_cast<const bf16x8*>(&pl[wid][16 + lcol][kf2 * 32 + lrow * 8]);
#pragma unroll
            for (int nf = 0; nf < 4; ++nf) {
                bf16x8 bv = *reinterpret_cast<const bf16x8*>(&vt[nf * 16 + lcol][kf2 * 32 + lrow * 8]);
                oacc[0][nf] = MFMA16(ap0, bv, oacc[0][nf]);
                oacc[1][nf] = MFMA16(ap1, bv, oacc[1][nf]);
            }
        }
        __syncthreads();
    }

#pragma unroll
    for (int m = 0; m < 2; ++m)
#pragma unroll
        for (int r = 0; r < 4; ++r) {
            float inv = 1.f / lrun[m][r];
            int tok = i * BS + wid * 32 + m * 16 + lrow * 4 + r;
            unsigned short* orow = Ob + (size_t)(b * T + tok) * D + hoff;
#pragma unroll
            for (int nf = 0; nf < 4; ++nf)
                orow[nf * 16 + lcol] = f2bf(oacc[m][nf][r] * inv);
        }
}

// ---------------- launch -------------------------------------------------------
extern "C" void kernel_launch(void* const* d_in, const int* in_sizes, int n_in,
                              void* d_out, int out_size, void* d_ws, size_t ws_size,
                              hipStream_t stream) {
    const float* x  = (const float*)d_in[0];
    const float* Wq = (const float*)d_in[1];
    const float* Wk = (const float*)d_in[2];
    const float* Wv = (const float*)d_in[3];
    const float* Wo = (const float*)d_in[4];

    constexpr int B = 2, T = 4096, D = 2048;
    constexpr int M = B * T;                    // 8192
    constexpr size_t XE = (size_t)M * D;
    constexpr size_t WE = (size_t)D * D;

    char* ws = (char*)d_ws;
    unsigned short* xb  = (unsigned short*)(ws);
    unsigned short* wqb = (unsigned short*)(ws + XE * 2);
    unsigned short* wkb = (unsigned short*)(ws + XE * 2 + WE * 2);
    unsigned short* wvb = (unsigned short*)(ws + XE * 2 + WE * 4);
    unsigned short* wob = (unsigned short*)(ws + XE * 2 + WE * 6);
    unsigned short* qb  = (unsigned short*)(ws + XE * 2 + WE * 8);
    unsigned short* kb  = (unsigned short*)(ws + XE * 4 + WE * 8);
    unsigned short* vb  = (unsigned short*)(ws + XE * 6 + WE * 8);
    unsigned short* ab  = (unsigned short*)(ws + XE * 8 + WE * 8);

    cvt_f32_bf16<<<2048, 256, 0, stream>>>(x,  xb,  (int)(XE / 8));
    cvt_f32_bf16<<<2048, 256, 0, stream>>>(Wq, wqb, (int)(WE / 8));
    cvt_f32_bf16<<<2048, 256, 0, stream>>>(Wk, wkb, (int)(WE / 8));
    cvt_f32_bf16<<<2048, 256, 0, stream>>>(Wv, wvb, (int)(WE / 8));
    cvt_f32_bf16<<<2048, 256, 0, stream>>>(Wo, wob, (int)(WE / 8));

    dim3 gg((M / 256) * (D / 256));   // 32*8 = 256 blocks
    gemm256<0><<<gg, 512, 0, stream>>>(xb, wqb, qb, M, D, D);
    gemm256<0><<<gg, 512, 0, stream>>>(xb, wkb, kb, M, D, D);
    gemm256<0><<<gg, 512, 0, stream>>>(xb, wvb, vb, M, D, D);

    swa_attn<<<dim3(32, 32, 2), 256, 0, stream>>>(qb, kb, vb, ab);

    gemm256<1><<<gg, 512, 0, stream>>>(ab, wob, d_out, M, D, D);
}

// Round 5
// 358.305 us; speedup vs baseline: 1.4551x; 1.0522x over previous
//
#include <hip/hip_runtime.h>
#include <hip/hip_bf16.h>

typedef __attribute__((ext_vector_type(8))) short bf16x8;
typedef __attribute__((ext_vector_type(8))) unsigned short ushort8;
typedef __attribute__((ext_vector_type(4))) float f32x4;
typedef __attribute__((ext_vector_type(2))) unsigned int u32x2;

#define MFMA16(a, b, c) __builtin_amdgcn_mfma_f32_16x16x32_bf16(a, b, c, 0, 0, 0)
#define CFENCE() asm volatile("" ::: "memory")

__device__ __forceinline__ unsigned short f2bf(float x) {
    unsigned u = __builtin_bit_cast(unsigned, x);
    u += 0x7FFFu + ((u >> 16) & 1u);
    return (unsigned short)(u >> 16);
}

__device__ __forceinline__ float fexp2(float x) {
#if __has_builtin(__builtin_amdgcn_exp2f)
    return __builtin_amdgcn_exp2f(x);
#else
    return exp2f(x);
#endif
}

__device__ __forceinline__ void gload16(const void* g, void* l) {
    __builtin_amdgcn_global_load_lds((const __attribute__((address_space(1))) void*)g,
                                     (__attribute__((address_space(3))) void*)l, 16, 0, 0);
}

__device__ __forceinline__ void bar() {
    asm volatile("" ::: "memory");
    __builtin_amdgcn_s_barrier();
    asm volatile("" ::: "memory");
}

#define WAITL() do { asm volatile("s_waitcnt lgkmcnt(0)" ::: "memory"); \
                     __builtin_amdgcn_sched_barrier(0); } while (0)

// ---------------- fp32 -> bf16 conversion (8 elems/thread/iter) ----------------
__global__ void cvt_f32_bf16(const float* __restrict__ src, unsigned short* __restrict__ dst, int n8) {
    int stride = gridDim.x * blockDim.x;
    for (int i = blockIdx.x * blockDim.x + threadIdx.x; i < n8; i += stride) {
        const float4* s = reinterpret_cast<const float4*>(src) + (size_t)i * 2;
        float4 a = s[0], b = s[1];
        ushort8 o;
        o[0] = f2bf(a.x); o[1] = f2bf(a.y); o[2] = f2bf(a.z); o[3] = f2bf(a.w);
        o[4] = f2bf(b.x); o[5] = f2bf(b.y); o[6] = f2bf(b.z); o[7] = f2bf(b.w);
        *(reinterpret_cast<ushort8*>(dst) + i) = o;
    }
}

// ---------------- 256x256 8-phase bf16 GEMM, C = A @ B^T ----------------------
// MODE 1: f32 store, stride N.  MODE 2: bf16 QKV-routed (N=6144 -> 3 x [M,2048]).
#define QUAD(mg, ng, bfv)                                                         \
    do {                                                                          \
        _Pragma("unroll") for (int mm = 0; mm < 4; ++mm)                          \
        _Pragma("unroll") for (int nn = 0; nn < 2; ++nn)                          \
        _Pragma("unroll") for (int kk = 0; kk < 2; ++kk)                          \
            acc[(mg) * 4 + mm][(ng) * 2 + nn] =                                   \
                MFMA16(af[mm][kk], bfv[nn][kk], acc[(mg) * 4 + mm][(ng) * 2 + nn]); \
    } while (0)

template <int MODE>
__global__ __launch_bounds__(512, 2)
void gemm256(const unsigned short* __restrict__ A, const unsigned short* __restrict__ B,
             void* __restrict__ C, int M, int N, int K) {
    __shared__ char sm[131072];   // A: [0,64K) = d*32K + h*16K ; B: [64K,128K)

    const int tid  = threadIdx.x;
    const int wid  = tid >> 6, lane = tid & 63;
    const int wr   = wid >> 2, wc = wid & 3;
    const int lrow = lane >> 4, lcol = lane & 15;

    const int flat = blockIdx.x;
    const int s = (flat & 7) * (gridDim.x >> 3) + (flat >> 3);
    const int nbn = N >> 8;
    const int bm = s / nbn, bn = s % nbn;

    const int srow = wid * 8 + (lane >> 3);
    const int scol = ((lane & 7) ^ ((lane >> 3) & 7)) * 8;
    const unsigned short* aS = A + (size_t)(bm * 256 + srow) * K + scol;
    const unsigned short* bS = B + (size_t)(bn * 256 + srow) * K + scol;
    const int ldsW = wid * 1024;

    auto stageA = [&](int d, int h, int t) {
#pragma unroll
        for (int q = 0; q < 2; ++q)
            gload16(aS + (size_t)(h * 128 + q * 64) * K + t * 64,
                    sm + d * 32768 + h * 16384 + ldsW + q * 8192);
    };
    auto stageB = [&](int d, int h, int t) {
#pragma unroll
        for (int q = 0; q < 2; ++q)
            gload16(bS + (size_t)(h * 128 + q * 64) * K + t * 64,
                    sm + 65536 + d * 32768 + h * 16384 + ldsW + q * 8192);
    };

    const int swz0 = (lrow * 16) ^ ((lcol & 7) << 4);
    const int swz1 = (64 + lrow * 16) ^ ((lcol & 7) << 4);
    const int ra = wr * 16 + lcol;
    const int rb = wc * 16 + lcol;

    bf16x8 af[4][2], bl[2][2], bh[2][2];
    auto loadA = [&](int d, int mg) {
#pragma unroll
        for (int mm = 0; mm < 4; ++mm) {
            af[mm][0] = *(const bf16x8*)(sm + d * 32768 + mg * 16384 + (mm * 32 + ra) * 128 + swz0);
            af[mm][1] = *(const bf16x8*)(sm + d * 32768 + mg * 16384 + (mm * 32 + ra) * 128 + swz1);
        }
    };
    auto loadB = [&](int d, int ng, bf16x8 (&bfv)[2][2]) {
#pragma unroll
        for (int nn = 0; nn < 2; ++nn) {
            bfv[nn][0] = *(const bf16x8*)(sm + 65536 + d * 32768 + ng * 16384 + (nn * 64 + rb) * 128 + swz0);
            bfv[nn][1] = *(const bf16x8*)(sm + 65536 + d * 32768 + ng * 16384 + (nn * 64 + rb) * 128 + swz1);
        }
    };

    f32x4 acc[8][4] = {};

    stageA(0, 0, 0); stageB(0, 0, 0); stageB(0, 1, 0); stageA(0, 1, 0);
    stageA(1, 0, 1); stageB(1, 0, 1); stageB(1, 1, 1);
    asm volatile("s_waitcnt vmcnt(6)" ::: "memory");
    bar();

    const int NI = K / 128;
#pragma unroll 1
    for (int i = 0; i < NI; ++i) {
        const int t0 = 2 * i;
        const bool last = (i == NI - 1);
        loadA(0, 0); loadB(0, 0, bl);
        stageA(1, 1, t0 + 1);
        bar(); WAITL();
        __builtin_amdgcn_s_setprio(1); QUAD(0, 0, bl); __builtin_amdgcn_s_setprio(0);
        bar();
        loadB(0, 1, bh);
        if (!last) stageA(0, 0, t0 + 2);
        bar(); WAITL();
        __builtin_amdgcn_s_setprio(1); QUAD(0, 1, bh); __builtin_amdgcn_s_setprio(0);
        bar();
        loadA(0, 1);
        if (!last) stageB(0, 0, t0 + 2);
        bar(); WAITL();
        __builtin_amdgcn_s_setprio(1); QUAD(1, 0, bl); __builtin_amdgcn_s_setprio(0);
        bar();
        if (!last) stageB(0, 1, t0 + 2);
        bar();
        __builtin_amdgcn_s_setprio(1); QUAD(1, 1, bh); __builtin_amdgcn_s_setprio(0);
        if (last) asm volatile("s_waitcnt vmcnt(0)" ::: "memory");
        else      asm volatile("s_waitcnt vmcnt(6)" ::: "memory");
        bar();
        loadA(1, 0); loadB(1, 0, bl);
        if (!last) stageA(0, 1, t0 + 2);
        bar(); WAITL();
        __builtin_amdgcn_s_setprio(1); QUAD(0, 0, bl); __builtin_amdgcn_s_setprio(0);
        bar();
        loadB(1, 1, bh);
        if (!last) stageA(1, 0, t0 + 3);
        bar(); WAITL();
        __builtin_amdgcn_s_setprio(1); QUAD(0, 1, bh); __builtin_amdgcn_s_setprio(0);
        bar();
        loadA(1, 1);
        if (!last) stageB(1, 0, t0 + 3);
        bar(); WAITL();
        __builtin_amdgcn_s_setprio(1); QUAD(1, 0, bl); __builtin_amdgcn_s_setprio(0);
        bar();
        if (!last) stageB(1, 1, t0 + 3);
        bar();
        __builtin_amdgcn_s_setprio(1); QUAD(1, 1, bh); __builtin_amdgcn_s_setprio(0);
        if (!last) asm volatile("s_waitcnt vmcnt(6)" ::: "memory");
        bar();
    }

    const size_t row0 = (size_t)bm * 256 + wr * 16 + lrow * 4;
    if (MODE == 1) {
        const int col0 = bn * 256 + wc * 16 + lcol;
#pragma unroll
        for (int m = 0; m < 8; ++m)
#pragma unroll
            for (int n = 0; n < 4; ++n)
#pragma unroll
                for (int r = 0; r < 4; ++r)
                    ((float*)C)[(row0 + m * 32 + r) * N + col0 + n * 64] = acc[m][n][r];
    } else {
        const int seg = (bn * 256) >> 11;                       // which of Q/K/V
        const int coll = bn * 256 - seg * 2048 + wc * 16 + lcol;
        unsigned short* out = (unsigned short*)C + (size_t)seg * 16777216ull;
#pragma unroll
        for (int m = 0; m < 8; ++m)
#pragma unroll
            for (int n = 0; n < 4; ++n)
#pragma unroll
                for (int r = 0; r < 4; ++r)
                    out[(row0 + m * 32 + r) * 2048 + coll + n * 64] = f2bf(acc[m][n][r]);
    }
}

// ---------------- sliding-window attention (swapped ops, de-risked LDS) --------
// 2048 blocks x 256 thr (4 waves x 32 q). Swapped QK^T: mfma(K, Q) -> lane owns
// q-row = lcol, softmax reduce = 2 shuffles. Swapped PV: mfma(V^T, P^T) with
// V^T from round-2-validated vt[64][136] scatter stage, P via per-wave LDS slice
// (scalar ushort writes -> lgkmcnt(0) -> bf16x8 reads). No tr_read / cvt_pk /
// V-DMA this round (round-3/4 failure isolated to that cluster).
__global__ __launch_bounds__(256, 3)
void swa_attn(const unsigned short* __restrict__ Qb, const unsigned short* __restrict__ Kb,
              const unsigned short* __restrict__ Vb, unsigned short* __restrict__ Ob) {
    constexpr int T = 4096, D = 2048;
    constexpr float SC = 0.18033688011112042f;   // log2(e)/8  (exp2 domain)

    __shared__ unsigned short vt[64][136];       // V^T chunk: [d][kt]  (34 KB... 17.4 KB)
    __shared__ unsigned short pls[4][32][40];    // per-wave P slice: [q][kt32], row 80 B

    const int bid  = blockIdx.x;
    const int flat = (bid & 7) * 256 + (bid >> 3);   // XCD-contiguous i-ranges
    const int i = flat & 31, h = (flat >> 5) & 31, b = flat >> 10;

    const int tid = threadIdx.x, wid = tid >> 6, lane = tid & 63;
    const int lcol = lane & 15, lrow = lane >> 4;

    const unsigned short* qp = Qb + (size_t)b * T * D + h * 64;
    const unsigned short* kp = Kb + (size_t)b * T * D + h * 64;
    const unsigned short* vp = Vb + (size_t)b * T * D + h * 64;

    const int t0 = (i == 0) ? 1 : 0;

    // Q fragments (B-operand of QK^T), held in regs
    const int q0 = i * 128 + wid * 32;
    bf16x8 aq[2][2];
#pragma unroll
    for (int qg = 0; qg < 2; ++qg)
#pragma unroll
        for (int kf = 0; kf < 2; ++kf)
            aq[qg][kf] = *(const bf16x8*)(qp + (size_t)(q0 + qg * 16 + lcol) * D + kf * 32 + lrow * 8);

    f32x4 oacc[2][4] = {};
    float mrun[2] = {-1e30f, -1e30f}, lrun[2] = {0.f, 0.f};

#pragma unroll 1
    for (int t = t0; t < 2; ++t) {
        const int kt0 = (i - 1 + t) * 128;

        // ---- stage V^T (round-2-validated scatter: coalesced 16B reads, b16 writes)
#pragma unroll
        for (int it = 0; it < 4; ++it) {
            int e = it * 2048 + tid * 8;
            int kr = e >> 6;
            int dc = e & 63;
            bf16x8 v = *(const bf16x8*)(vp + (size_t)(kt0 + kr) * D + dc);
#pragma unroll
            for (int j = 0; j < 8; ++j) vt[dc + j][kr] = (unsigned short)v[j];
        }

        // ---- S^T = mfma(K, Q): lane holds S[q = qg*16+lcol][kt = 16n+4lrow+r] ----
        f32x4 s[2][8];
#pragma unroll
        for (int n = 0; n < 8; ++n) {
            const unsigned short* krow = kp + (size_t)(kt0 + n * 16 + lcol) * D + lrow * 8;
            bf16x8 k0 = *(const bf16x8*)(krow);
            bf16x8 k1 = *(const bf16x8*)(krow + 32);
            f32x4 z = {0.f, 0.f, 0.f, 0.f};
            s[0][n] = MFMA16(k1, aq[0][1], MFMA16(k0, aq[0][0], z));
            s[1][n] = MFMA16(k1, aq[1][1], MFMA16(k0, aq[1][0], z));
        }

        // ---- mask + scale into exp2 domain ----
#pragma unroll
        for (int qg = 0; qg < 2; ++qg) {
            const int q = wid * 32 + qg * 16 + lcol;
#pragma unroll
            for (int n = 0; n < 8; ++n) {
                const int cb = t * 128 + n * 16 + lrow * 4 - q;
#pragma unroll
                for (int r = 0; r < 4; ++r)
                    s[qg][n][r] = ((unsigned)(cb + r) <= 128u) ? s[qg][n][r] * SC : -1e30f;
            }
        }

        // ---- online softmax (row stats across lanes {l, l^16, l^32}) ----
#pragma unroll
        for (int qg = 0; qg < 2; ++qg) {
            float cm = -1e30f;
#pragma unroll
            for (int n = 0; n < 8; ++n)
#pragma unroll
                for (int r = 0; r < 4; ++r) cm = fmaxf(cm, s[qg][n][r]);
            cm = fmaxf(cm, __shfl_xor(cm, 16));
            cm = fmaxf(cm, __shfl_xor(cm, 32));
            const float mn = fmaxf(mrun[qg], cm);
            const float sf = fexp2(mrun[qg] - mn);
            mrun[qg] = mn;
            float rs = 0.f;
#pragma unroll
            for (int n = 0; n < 8; ++n)
#pragma unroll
                for (int r = 0; r < 4; ++r) {
                    float p = fexp2(s[qg][n][r] - mn);
                    s[qg][n][r] = p;
                    rs += p;
                }
            rs += __shfl_xor(rs, 16);
            rs += __shfl_xor(rs, 32);
            lrun[qg] = lrun[qg] * sf + rs;
#pragma unroll
            for (int nf = 0; nf < 4; ++nf) oacc[qg][nf] *= sf;
        }

        __syncthreads();   // vt writes visible to all waves

        // ---- O^T += mfma(V^T, P^T), per 32-kt slice ----
#pragma unroll
        for (int ks = 0; ks < 4; ++ks) {
            CFENCE();
            // P slice -> per-wave LDS (scalar stores; kt = 32ks + e, e = 0..31)
#pragma unroll
            for (int qg = 0; qg < 2; ++qg) {
                unsigned short* prow = &pls[wid][qg * 16 + lcol][0];
#pragma unroll
                for (int r = 0; r < 4; ++r) {
                    prow[4 * lrow + r]      = f2bf(s[qg][2 * ks][r]);
                    prow[16 + 4 * lrow + r] = f2bf(s[qg][2 * ks + 1][r]);
                }
            }
            CFENCE();
            WAITL();   // drain ds_writes before same-wave cross-lane reads
            bf16x8 pf0 = *(const bf16x8*)&pls[wid][lcol][lrow * 8];
            bf16x8 pf1 = *(const bf16x8*)&pls[wid][16 + lcol][lrow * 8];
#pragma unroll
            for (int nf = 0; nf < 4; ++nf) {
                bf16x8 av = *(const bf16x8*)&vt[nf * 16 + lcol][ks * 32 + lrow * 8];
                oacc[0][nf] = MFMA16(av, pf0, oacc[0][nf]);
                oacc[1][nf] = MFMA16(av, pf1, oacc[1][nf]);
            }
            CFENCE();
        }

        __syncthreads();   // PV reads done before next chunk restages vt
    }

    // ---- normalize + store: lane owns q = lcol, d = 16nf + 4lrow + r ----
#pragma unroll
    for (int qg = 0; qg < 2; ++qg) {
        const float inv = 1.f / lrun[qg];
        const int tok = i * 128 + wid * 32 + qg * 16 + lcol;
        unsigned short* orow = Ob + (size_t)(b * T + tok) * D + h * 64;
#pragma unroll
        for (int nf = 0; nf < 4; ++nf) {
            unsigned o0 = (unsigned)f2bf(oacc[qg][nf][0] * inv) |
                          ((unsigned)f2bf(oacc[qg][nf][1] * inv) << 16);
            unsigned o1 = (unsigned)f2bf(oacc[qg][nf][2] * inv) |
                          ((unsigned)f2bf(oacc[qg][nf][3] * inv) << 16);
            *(u32x2*)(orow + nf * 16 + lrow * 4) = (u32x2){o0, o1};
        }
    }
}

// ---------------- launch -------------------------------------------------------
extern "C" void kernel_launch(void* const* d_in, const int* in_sizes, int n_in,
                              void* d_out, int out_size, void* d_ws, size_t ws_size,
                              hipStream_t stream) {
    const float* x  = (const float*)d_in[0];
    const float* Wq = (const float*)d_in[1];
    const float* Wk = (const float*)d_in[2];
    const float* Wv = (const float*)d_in[3];
    const float* Wo = (const float*)d_in[4];

    constexpr int B = 2, T = 4096, D = 2048;
    constexpr int M = B * T;                    // 8192
    constexpr size_t XE = (size_t)M * D;
    constexpr size_t WE = (size_t)D * D;

    char* ws = (char*)d_ws;
    unsigned short* xb  = (unsigned short*)(ws);
    unsigned short* wqb = (unsigned short*)(ws + XE * 2);               // Wq,Wk,Wv contiguous
    unsigned short* wkb = (unsigned short*)(ws + XE * 2 + WE * 2);
    unsigned short* wvb = (unsigned short*)(ws + XE * 2 + WE * 4);
    unsigned short* wob = (unsigned short*)(ws + XE * 2 + WE * 6);
    unsigned short* qb  = (unsigned short*)(ws + XE * 2 + WE * 8);      // Q,K,V contiguous
    unsigned short* kb  = (unsigned short*)(ws + XE * 4 + WE * 8);
    unsigned short* vb  = (unsigned short*)(ws + XE * 6 + WE * 8);
    unsigned short* ab  = (unsigned short*)(ws + XE * 8 + WE * 8);

    cvt_f32_bf16<<<2048, 256, 0, stream>>>(x,  xb,  (int)(XE / 8));
    cvt_f32_bf16<<<2048, 256, 0, stream>>>(Wq, wqb, (int)(WE / 8));
    cvt_f32_bf16<<<2048, 256, 0, stream>>>(Wk, wkb, (int)(WE / 8));
    cvt_f32_bf16<<<2048, 256, 0, stream>>>(Wv, wvb, (int)(WE / 8));
    cvt_f32_bf16<<<2048, 256, 0, stream>>>(Wo, wob, (int)(WE / 8));

    // fused QKV projection: C = x @ [Wq;Wk;Wv]^T, routed to qb/kb/vb
    gemm256<2><<<dim3((M / 256) * (6144 / 256)), 512, 0, stream>>>(xb, wqb, qb, M, 6144, D);

    swa_attn<<<dim3(2048), 256, 0, stream>>>(qb, kb, vb, ab);

    gemm256<1><<<dim3((M / 256) * (D / 256)), 512, 0, stream>>>(ab, wob, d_out, M, D, D);
}

// Round 6
// 357.301 us; speedup vs baseline: 1.4592x; 1.0028x over previous
//
#include <hip/hip_runtime.h>
#include <hip/hip_bf16.h>

typedef __attribute__((ext_vector_type(8))) short bf16x8;
typedef __attribute__((ext_vector_type(8))) unsigned short ushort8;
typedef __attribute__((ext_vector_type(4))) float f32x4;
typedef __attribute__((ext_vector_type(2))) unsigned int u32x2;

#define MFMA16(a, b, c) __builtin_amdgcn_mfma_f32_16x16x32_bf16(a, b, c, 0, 0, 0)
#define CFENCE() asm volatile("" ::: "memory")

__device__ __forceinline__ unsigned short f2bf(float x) {
    unsigned u = __builtin_bit_cast(unsigned, x);
    u += 0x7FFFu + ((u >> 16) & 1u);
    return (unsigned short)(u >> 16);
}

__device__ __forceinline__ float fexp2(float x) {
#if __has_builtin(__builtin_amdgcn_exp2f)
    return __builtin_amdgcn_exp2f(x);
#else
    return exp2f(x);
#endif
}

__device__ __forceinline__ void gload16(const void* g, void* l) {
    __builtin_amdgcn_global_load_lds((const __attribute__((address_space(1))) void*)g,
                                     (__attribute__((address_space(3))) void*)l, 16, 0, 0);
}

__device__ __forceinline__ void bar() {
    asm volatile("" ::: "memory");
    __builtin_amdgcn_s_barrier();
    asm volatile("" ::: "memory");
}

#define WAITL() do { asm volatile("s_waitcnt lgkmcnt(0)" ::: "memory"); \
                     __builtin_amdgcn_sched_barrier(0); } while (0)

// ---------------- fused fp32 -> bf16 conversion (x + 4 weights, 1 launch) ------
// dst layout is contiguous: [x: XE][Wq: WE][Wk: WE][Wv: WE][Wo: WE]
__global__ void cvt_all(const float* __restrict__ x, const float* __restrict__ wq,
                        const float* __restrict__ wk, const float* __restrict__ wv,
                        const float* __restrict__ wo, unsigned short* __restrict__ dst,
                        int total8) {
    constexpr int XE8 = 2097152;   // (8192*2048)/8
    constexpr int WE8 = 524288;    // (2048*2048)/8
    int stride = gridDim.x * blockDim.x;
    for (int i = blockIdx.x * blockDim.x + threadIdx.x; i < total8; i += stride) {
        const float* src;
        if (i < XE8) {
            src = x + (size_t)i * 8;
        } else {
            int k = i - XE8;
            int seg = k >> 19;              // WE8 = 2^19
            int off = k & (WE8 - 1);
            const float* w = (seg == 0) ? wq : (seg == 1) ? wk : (seg == 2) ? wv : wo;
            src = w + (size_t)off * 8;
        }
        const float4* s = (const float4*)src;
        float4 a = s[0], b = s[1];
        ushort8 o;
        o[0] = f2bf(a.x); o[1] = f2bf(a.y); o[2] = f2bf(a.z); o[3] = f2bf(a.w);
        o[4] = f2bf(b.x); o[5] = f2bf(b.y); o[6] = f2bf(b.z); o[7] = f2bf(b.w);
        *(reinterpret_cast<ushort8*>(dst) + i) = o;
    }
}

// ---------------- 256x256 8-phase bf16 GEMM, C = A @ B^T ----------------------
// MODE 1: f32 store, stride N.  MODE 2: bf16 QKV-routed (N=6144 -> 3 x [M,2048]).
// R6: supertile block mapping (4 bm x nbn per XCD chunk, co-resident = 4x8 panel
// group) + stage rebalance (4th half staged at P3/P7 -> uniform vmcnt(8) gates,
// newest-half slack 4-5 phases).
#define QUAD(mg, ng, bfv)                                                         \
    do {                                                                          \
        _Pragma("unroll") for (int mm = 0; mm < 4; ++mm)                          \
        _Pragma("unroll") for (int nn = 0; nn < 2; ++nn)                          \
        _Pragma("unroll") for (int kk = 0; kk < 2; ++kk)                          \
            acc[(mg) * 4 + mm][(ng) * 2 + nn] =                                   \
                MFMA16(af[mm][kk], bfv[nn][kk], acc[(mg) * 4 + mm][(ng) * 2 + nn]); \
    } while (0)

template <int MODE>
__global__ __launch_bounds__(512, 2)
void gemm256(const unsigned short* __restrict__ A, const unsigned short* __restrict__ B,
             void* __restrict__ C, int M, int N, int K) {
    __shared__ char sm[131072];   // A: [0,64K) = d*32K + h*16K ; B: [64K,128K)

    const int tid  = threadIdx.x;
    const int wid  = tid >> 6, lane = tid & 63;
    const int wr   = wid >> 2, wc = wid & 3;
    const int lrow = lane >> 4, lcol = lane & 15;

    // XCD chunk + supertile: bm rows disjoint per XCD; co-resident 32 blocks
    // cover 4 bm x 8 bn -> 12 panel-slices per K-step into one L2.
    const int nbm = M >> 8;
    const int rpx = nbm >> 3;                 // bm rows per XCD (=4)
    const int xcd = blockIdx.x & 7;
    const int l   = blockIdx.x >> 3;
    const int bm  = xcd * rpx + (l & (rpx - 1));
    const int bn  = l / rpx;

    const int srow = wid * 8 + (lane >> 3);
    const int scol = ((lane & 7) ^ ((lane >> 3) & 7)) * 8;
    const unsigned short* aS = A + (size_t)(bm * 256 + srow) * K + scol;
    const unsigned short* bS = B + (size_t)(bn * 256 + srow) * K + scol;
    const int ldsW = wid * 1024;

    auto stageA = [&](int d, int h, int t) {
#pragma unroll
        for (int q = 0; q < 2; ++q)
            gload16(aS + (size_t)(h * 128 + q * 64) * K + t * 64,
                    sm + d * 32768 + h * 16384 + ldsW + q * 8192);
    };
    auto stageB = [&](int d, int h, int t) {
#pragma unroll
        for (int q = 0; q < 2; ++q)
            gload16(bS + (size_t)(h * 128 + q * 64) * K + t * 64,
                    sm + 65536 + d * 32768 + h * 16384 + ldsW + q * 8192);
    };

    const int swz0 = (lrow * 16) ^ ((lcol & 7) << 4);
    const int swz1 = (64 + lrow * 16) ^ ((lcol & 7) << 4);
    const int ra = wr * 16 + lcol;
    const int rb = wc * 16 + lcol;

    bf16x8 af[4][2], bl[2][2], bh[2][2];
    auto loadA = [&](int d, int mg) {
#pragma unroll
        for (int mm = 0; mm < 4; ++mm) {
            af[mm][0] = *(const bf16x8*)(sm + d * 32768 + mg * 16384 + (mm * 32 + ra) * 128 + swz0);
            af[mm][1] = *(const bf16x8*)(sm + d * 32768 + mg * 16384 + (mm * 32 + ra) * 128 + swz1);
        }
    };
    auto loadB = [&](int d, int ng, bf16x8 (&bfv)[2][2]) {
#pragma unroll
        for (int nn = 0; nn < 2; ++nn) {
            bfv[nn][0] = *(const bf16x8*)(sm + 65536 + d * 32768 + ng * 16384 + (nn * 64 + rb) * 128 + swz0);
            bfv[nn][1] = *(const bf16x8*)(sm + 65536 + d * 32768 + ng * 16384 + (nn * 64 + rb) * 128 + swz1);
        }
    };

    f32x4 acc[8][4] = {};

    // prologue: buf0 (tile0) then buf1 (tile1), 8 loads each; drain buf0.
    stageA(0, 0, 0); stageB(0, 0, 0); stageB(0, 1, 0); stageA(0, 1, 0);
    stageA(1, 0, 1); stageB(1, 0, 1); stageB(1, 1, 1); stageA(1, 1, 1);
    asm volatile("s_waitcnt vmcnt(8)" ::: "memory");
    bar();

    const int NI = K / 128;
#pragma unroll 1
    for (int i = 0; i < NI; ++i) {
        const int t0 = 2 * i;
        const bool last = (i == NI - 1);
        // ---- P0: buf0, m-low x n-low (no stage this phase) ----
        loadA(0, 0); loadB(0, 0, bl);
        bar(); WAITL();
        __builtin_amdgcn_s_setprio(1); QUAD(0, 0, bl); __builtin_amdgcn_s_setprio(0);
        bar();
        // ---- P1 ----
        loadB(0, 1, bh);
        if (!last) stageA(0, 0, t0 + 2);
        bar(); WAITL();
        __builtin_amdgcn_s_setprio(1); QUAD(0, 1, bh); __builtin_amdgcn_s_setprio(0);
        bar();
        // ---- P2 ----
        loadA(0, 1);
        if (!last) stageB(0, 0, t0 + 2);
        bar(); WAITL();
        __builtin_amdgcn_s_setprio(1); QUAD(1, 0, bl); __builtin_amdgcn_s_setprio(0);
        bar();
        // ---- P3: stage both remaining buf0(t+2) halves; gate buf1(t0+1) ----
        if (!last) { stageB(0, 1, t0 + 2); stageA(0, 1, t0 + 2); }
        bar();
        __builtin_amdgcn_s_setprio(1); QUAD(1, 1, bh); __builtin_amdgcn_s_setprio(0);
        if (last) asm volatile("s_waitcnt vmcnt(0)" ::: "memory");
        else      asm volatile("s_waitcnt vmcnt(8)" ::: "memory");
        bar();
        // ---- P4: buf1, m-low x n-low (no stage) ----
        loadA(1, 0); loadB(1, 0, bl);
        bar(); WAITL();
        __builtin_amdgcn_s_setprio(1); QUAD(0, 0, bl); __builtin_amdgcn_s_setprio(0);
        bar();
        // ---- P5 ----
        loadB(1, 1, bh);
        if (!last) stageA(1, 0, t0 + 3);
        bar(); WAITL();
        __builtin_amdgcn_s_setprio(1); QUAD(0, 1, bh); __builtin_amdgcn_s_setprio(0);
        bar();
        // ---- P6 ----
        loadA(1, 1);
        if (!last) stageB(1, 0, t0 + 3);
        bar(); WAITL();
        __builtin_amdgcn_s_setprio(1); QUAD(1, 0, bl); __builtin_amdgcn_s_setprio(0);
        bar();
        // ---- P7: stage both remaining buf1(t+3) halves; gate buf0(t0+2) ----
        if (!last) { stageB(1, 1, t0 + 3); stageA(1, 1, t0 + 3); }
        bar();
        __builtin_amdgcn_s_setprio(1); QUAD(1, 1, bh); __builtin_amdgcn_s_setprio(0);
        if (!last) asm volatile("s_waitcnt vmcnt(8)" ::: "memory");
        bar();
    }

    const size_t row0 = (size_t)bm * 256 + wr * 16 + lrow * 4;
    if (MODE == 1) {
        const int col0 = bn * 256 + wc * 16 + lcol;
#pragma unroll
        for (int m = 0; m < 8; ++m)
#pragma unroll
            for (int n = 0; n < 4; ++n)
#pragma unroll
                for (int r = 0; r < 4; ++r)
                    ((float*)C)[(row0 + m * 32 + r) * N + col0 + n * 64] = acc[m][n][r];
    } else {
        const int seg = (bn * 256) >> 11;                       // which of Q/K/V
        const int coll = bn * 256 - seg * 2048 + wc * 16 + lcol;
        unsigned short* out = (unsigned short*)C + (size_t)seg * 16777216ull;
#pragma unroll
        for (int m = 0; m < 8; ++m)
#pragma unroll
            for (int n = 0; n < 4; ++n)
#pragma unroll
                for (int r = 0; r < 4; ++r)
                    out[(row0 + m * 32 + r) * 2048 + coll + n * 64] = f2bf(acc[m][n][r]);
    }
}

// ---------------- sliding-window attention (swapped ops, de-risked LDS) --------
// 2048 blocks x 256 thr (4 waves x 32 q). Swapped QK^T: mfma(K, Q) -> lane owns
// q-row = lcol, softmax reduce = 2 shuffles. Swapped PV: mfma(V^T, P^T) with
// V^T from validated vt[64][136] scatter stage, P via per-wave LDS slice.
__global__ __launch_bounds__(256, 3)
void swa_attn(const unsigned short* __restrict__ Qb, const unsigned short* __restrict__ Kb,
              const unsigned short* __restrict__ Vb, unsigned short* __restrict__ Ob) {
    constexpr int T = 4096, D = 2048;
    constexpr float SC = 0.18033688011112042f;   // log2(e)/8  (exp2 domain)

    __shared__ unsigned short vt[64][136];       // V^T chunk: [d][kt]
    __shared__ unsigned short pls[4][32][40];    // per-wave P slice: [q][kt32]

    const int bid  = blockIdx.x;
    const int flat = (bid & 7) * 256 + (bid >> 3);   // XCD-contiguous i-ranges
    const int i = flat & 31, h = (flat >> 5) & 31, b = flat >> 10;

    const int tid = threadIdx.x, wid = tid >> 6, lane = tid & 63;
    const int lcol = lane & 15, lrow = lane >> 4;

    const unsigned short* qp = Qb + (size_t)b * T * D + h * 64;
    const unsigned short* kp = Kb + (size_t)b * T * D + h * 64;
    const unsigned short* vp = Vb + (size_t)b * T * D + h * 64;

    const int t0 = (i == 0) ? 1 : 0;

    // Q fragments (B-operand of QK^T), held in regs
    const int q0 = i * 128 + wid * 32;
    bf16x8 aq[2][2];
#pragma unroll
    for (int qg = 0; qg < 2; ++qg)
#pragma unroll
        for (int kf = 0; kf < 2; ++kf)
            aq[qg][kf] = *(const bf16x8*)(qp + (size_t)(q0 + qg * 16 + lcol) * D + kf * 32 + lrow * 8);

    f32x4 oacc[2][4] = {};
    float mrun[2] = {-1e30f, -1e30f}, lrun[2] = {0.f, 0.f};

#pragma unroll 1
    for (int t = t0; t < 2; ++t) {
        const int kt0 = (i - 1 + t) * 128;

        // ---- stage V^T (coalesced 16B reads, b16 scatter writes) ----
#pragma unroll
        for (int it = 0; it < 4; ++it) {
            int e = it * 2048 + tid * 8;
            int kr = e >> 6;
            int dc = e & 63;
            bf16x8 v = *(const bf16x8*)(vp + (size_t)(kt0 + kr) * D + dc);
#pragma unroll
            for (int j = 0; j < 8; ++j) vt[dc + j][kr] = (unsigned short)v[j];
        }

        // ---- S^T = mfma(K, Q): lane holds S[q = qg*16+lcol][kt = 16n+4lrow+r] ----
        f32x4 s[2][8];
#pragma unroll
        for (int n = 0; n < 8; ++n) {
            const unsigned short* krow = kp + (size_t)(kt0 + n * 16 + lcol) * D + lrow * 8;
            bf16x8 k0 = *(const bf16x8*)(krow);
            bf16x8 k1 = *(const bf16x8*)(krow + 32);
            f32x4 z = {0.f, 0.f, 0.f, 0.f};
            s[0][n] = MFMA16(k1, aq[0][1], MFMA16(k0, aq[0][0], z));
            s[1][n] = MFMA16(k1, aq[1][1], MFMA16(k0, aq[1][0], z));
        }

        // ---- mask + scale into exp2 domain ----
#pragma unroll
        for (int qg = 0; qg < 2; ++qg) {
            const int q = wid * 32 + qg * 16 + lcol;
#pragma unroll
            for (int n = 0; n < 8; ++n) {
                const int cb = t * 128 + n * 16 + lrow * 4 - q;
#pragma unroll
                for (int r = 0; r < 4; ++r)
                    s[qg][n][r] = ((unsigned)(cb + r) <= 128u) ? s[qg][n][r] * SC : -1e30f;
            }
        }

        // ---- online softmax (row stats across lanes {l, l^16, l^32}) ----
#pragma unroll
        for (int qg = 0; qg < 2; ++qg) {
            float cm = -1e30f;
#pragma unroll
            for (int n = 0; n < 8; ++n)
#pragma unroll
                for (int r = 0; r < 4; ++r) cm = fmaxf(cm, s[qg][n][r]);
            cm = fmaxf(cm, __shfl_xor(cm, 16));
            cm = fmaxf(cm, __shfl_xor(cm, 32));
            const float mn = fmaxf(mrun[qg], cm);
            const float sf = fexp2(mrun[qg] - mn);
            mrun[qg] = mn;
            float rs = 0.f;
#pragma unroll
            for (int n = 0; n < 8; ++n)
#pragma unroll
                for (int r = 0; r < 4; ++r) {
                    float p = fexp2(s[qg][n][r] - mn);
                    s[qg][n][r] = p;
                    rs += p;
                }
            rs += __shfl_xor(rs, 16);
            rs += __shfl_xor(rs, 32);
            lrun[qg] = lrun[qg] * sf + rs;
#pragma unroll
            for (int nf = 0; nf < 4; ++nf) oacc[qg][nf] *= sf;
        }

        __syncthreads();   // vt writes visible to all waves

        // ---- O^T += mfma(V^T, P^T), per 32-kt slice ----
#pragma unroll
        for (int ks = 0; ks < 4; ++ks) {
            CFENCE();
#pragma unroll
            for (int qg = 0; qg < 2; ++qg) {
                unsigned short* prow = &pls[wid][qg * 16 + lcol][0];
#pragma unroll
                for (int r = 0; r < 4; ++r) {
                    prow[4 * lrow + r]      = f2bf(s[qg][2 * ks][r]);
                    prow[16 + 4 * lrow + r] = f2bf(s[qg][2 * ks + 1][r]);
                }
            }
            CFENCE();
            WAITL();   // drain ds_writes before same-wave cross-lane reads
            bf16x8 pf0 = *(const bf16x8*)&pls[wid][lcol][lrow * 8];
            bf16x8 pf1 = *(const bf16x8*)&pls[wid][16 + lcol][lrow * 8];
#pragma unroll
            for (int nf = 0; nf < 4; ++nf) {
                bf16x8 av = *(const bf16x8*)&vt[nf * 16 + lcol][ks * 32 + lrow * 8];
                oacc[0][nf] = MFMA16(av, pf0, oacc[0][nf]);
                oacc[1][nf] = MFMA16(av, pf1, oacc[1][nf]);
            }
            CFENCE();
        }

        __syncthreads();   // PV reads done before next chunk restages vt
    }

    // ---- normalize + store: lane owns q = lcol, d = 16nf + 4lrow + r ----
#pragma unroll
    for (int qg = 0; qg < 2; ++qg) {
        const float inv = 1.f / lrun[qg];
        const int tok = i * 128 + wid * 32 + qg * 16 + lcol;
        unsigned short* orow = Ob + (size_t)(b * T + tok) * D + h * 64;
#pragma unroll
        for (int nf = 0; nf < 4; ++nf) {
            unsigned o0 = (unsigned)f2bf(oacc[qg][nf][0] * inv) |
                          ((unsigned)f2bf(oacc[qg][nf][1] * inv) << 16);
            unsigned o1 = (unsigned)f2bf(oacc[qg][nf][2] * inv) |
                          ((unsigned)f2bf(oacc[qg][nf][3] * inv) << 16);
            *(u32x2*)(orow + nf * 16 + lrow * 4) = (u32x2){o0, o1};
        }
    }
}

// ---------------- launch -------------------------------------------------------
extern "C" void kernel_launch(void* const* d_in, const int* in_sizes, int n_in,
                              void* d_out, int out_size, void* d_ws, size_t ws_size,
                              hipStream_t stream) {
    const float* x  = (const float*)d_in[0];
    const float* Wq = (const float*)d_in[1];
    const float* Wk = (const float*)d_in[2];
    const float* Wv = (const float*)d_in[3];
    const float* Wo = (const float*)d_in[4];

    constexpr int B = 2, T = 4096, D = 2048;
    constexpr int M = B * T;                    // 8192
    constexpr size_t XE = (size_t)M * D;
    constexpr size_t WE = (size_t)D * D;

    char* ws = (char*)d_ws;
    unsigned short* xb  = (unsigned short*)(ws);
    unsigned short* wqb = (unsigned short*)(ws + XE * 2);               // Wq,Wk,Wv contiguous
    unsigned short* qb  = (unsigned short*)(ws + XE * 2 + WE * 8);      // Q,K,V contiguous
    unsigned short* kb  = (unsigned short*)(ws + XE * 4 + WE * 8);
    unsigned short* vb  = (unsigned short*)(ws + XE * 6 + WE * 8);
    unsigned short* ab  = (unsigned short*)(ws + XE * 8 + WE * 8);

    // single fused conversion: x + Wq + Wk + Wv + Wo -> contiguous bf16 region
    cvt_all<<<2048, 256, 0, stream>>>(x, Wq, Wk, Wv, Wo, xb, (int)((XE + 4 * WE) / 8));

    // fused QKV projection: C = x @ [Wq;Wk;Wv]^T, routed to qb/kb/vb
    gemm256<2><<<dim3((M / 256) * (6144 / 256)), 512, 0, stream>>>(xb, wqb, qb, M, 6144, D);

    swa_attn<<<dim3(2048), 256, 0, stream>>>(qb, kb, vb, ab);

    gemm256<1><<<dim3((M / 256) * (D / 256)), 512, 0, stream>>>(ab, wqb + 3 * WE, d_out, M, D, D);
}

// Round 7
// 342.990 us; speedup vs baseline: 1.5201x; 1.0417x over previous
//
#include <hip/hip_runtime.h>
#include <hip/hip_bf16.h>

typedef __attribute__((ext_vector_type(8))) short bf16x8;
typedef __attribute__((ext_vector_type(8))) unsigned short ushort8;
typedef __attribute__((ext_vector_type(4))) float f32x4;
typedef __attribute__((ext_vector_type(2))) unsigned int u32x2;

#define MFMA16(a, b, c) __builtin_amdgcn_mfma_f32_16x16x32_bf16(a, b, c, 0, 0, 0)
#define CFENCE() asm volatile("" ::: "memory")

__device__ __forceinline__ unsigned short f2bf(float x) {
    unsigned u = __builtin_bit_cast(unsigned, x);
    u += 0x7FFFu + ((u >> 16) & 1u);
    return (unsigned short)(u >> 16);
}

__device__ __forceinline__ float fexp2(float x) {
#if __has_builtin(__builtin_amdgcn_exp2f)
    return __builtin_amdgcn_exp2f(x);
#else
    return exp2f(x);
#endif
}

__device__ __forceinline__ void gload16(const void* g, void* l) {
    __builtin_amdgcn_global_load_lds((const __attribute__((address_space(1))) void*)g,
                                     (__attribute__((address_space(3))) void*)l, 16, 0, 0);
}

__device__ __forceinline__ void bar() {
    asm volatile("" ::: "memory");
    __builtin_amdgcn_s_barrier();
    asm volatile("" ::: "memory");
}

#define WAITL() do { asm volatile("s_waitcnt lgkmcnt(0)" ::: "memory"); \
                     __builtin_amdgcn_sched_barrier(0); } while (0)

// ---------------- fused fp32 -> bf16 conversion (x + 4 weights, 1 launch) ------
__global__ void cvt_all(const float* __restrict__ x, const float* __restrict__ wq,
                        const float* __restrict__ wk, const float* __restrict__ wv,
                        const float* __restrict__ wo, unsigned short* __restrict__ dst,
                        int total8) {
    constexpr int XE8 = 2097152;   // (8192*2048)/8
    constexpr int WE8 = 524288;    // (2048*2048)/8
    int stride = gridDim.x * blockDim.x;
    for (int i = blockIdx.x * blockDim.x + threadIdx.x; i < total8; i += stride) {
        const float* src;
        if (i < XE8) {
            src = x + (size_t)i * 8;
        } else {
            int k = i - XE8;
            int seg = k >> 19;              // WE8 = 2^19
            int off = k & (WE8 - 1);
            const float* w = (seg == 0) ? wq : (seg == 1) ? wk : (seg == 2) ? wv : wo;
            src = w + (size_t)off * 8;
        }
        const float4* s = (const float4*)src;
        float4 a = s[0], b = s[1];
        ushort8 o;
        o[0] = f2bf(a.x); o[1] = f2bf(a.y); o[2] = f2bf(a.z); o[3] = f2bf(a.w);
        o[4] = f2bf(b.x); o[5] = f2bf(b.y); o[6] = f2bf(b.z); o[7] = f2bf(b.w);
        *(reinterpret_cast<ushort8*>(dst) + i) = o;
    }
}

// ---------------- 256x256 8-phase bf16 GEMM, C = A @ B^T ----------------------
// MODE 1: f32 store, stride N.  MODE 2: bf16 QKV-routed (N=6144 -> 3 x [M,2048]).
// R7: round-5 schedule (uniform 1 half-tile stage/phase, vmcnt(6) at P3/P7 —
// proven 196us/46% MfmaUtil) + round-6 supertile mapping (proven FETCH 2.2x cut).
#define QUAD(mg, ng, bfv)                                                         \
    do {                                                                          \
        _Pragma("unroll") for (int mm = 0; mm < 4; ++mm)                          \
        _Pragma("unroll") for (int nn = 0; nn < 2; ++nn)                          \
        _Pragma("unroll") for (int kk = 0; kk < 2; ++kk)                          \
            acc[(mg) * 4 + mm][(ng) * 2 + nn] =                                   \
                MFMA16(af[mm][kk], bfv[nn][kk], acc[(mg) * 4 + mm][(ng) * 2 + nn]); \
    } while (0)

template <int MODE>
__global__ __launch_bounds__(512, 2)
void gemm256(const unsigned short* __restrict__ A, const unsigned short* __restrict__ B,
             void* __restrict__ C, int M, int N, int K) {
    __shared__ char sm[131072];   // A: [0,64K) = d*32K + h*16K ; B: [64K,128K)

    const int tid  = threadIdx.x;
    const int wid  = tid >> 6, lane = tid & 63;
    const int wr   = wid >> 2, wc = wid & 3;
    const int lrow = lane >> 4, lcol = lane & 15;

    // supertile: co-resident 32 blocks per XCD form a 4 x 8 (bm x bn) panel group
    const int nbm = M >> 8;
    const int rpx = nbm >> 3;                 // bm rows per XCD (=4)
    const int xcd = blockIdx.x & 7;
    const int l   = blockIdx.x >> 3;
    const int bm  = xcd * rpx + (l & (rpx - 1));
    const int bn  = l / rpx;

    const int srow = wid * 8 + (lane >> 3);
    const int scol = ((lane & 7) ^ ((lane >> 3) & 7)) * 8;
    const unsigned short* aS = A + (size_t)(bm * 256 + srow) * K + scol;
    const unsigned short* bS = B + (size_t)(bn * 256 + srow) * K + scol;
    const int ldsW = wid * 1024;

    auto stageA = [&](int d, int h, int t) {
#pragma unroll
        for (int q = 0; q < 2; ++q)
            gload16(aS + (size_t)(h * 128 + q * 64) * K + t * 64,
                    sm + d * 32768 + h * 16384 + ldsW + q * 8192);
    };
    auto stageB = [&](int d, int h, int t) {
#pragma unroll
        for (int q = 0; q < 2; ++q)
            gload16(bS + (size_t)(h * 128 + q * 64) * K + t * 64,
                    sm + 65536 + d * 32768 + h * 16384 + ldsW + q * 8192);
    };

    const int swz0 = (lrow * 16) ^ ((lcol & 7) << 4);
    const int swz1 = (64 + lrow * 16) ^ ((lcol & 7) << 4);
    const int ra = wr * 16 + lcol;
    const int rb = wc * 16 + lcol;

    bf16x8 af[4][2], bl[2][2], bh[2][2];
    auto loadA = [&](int d, int mg) {
#pragma unroll
        for (int mm = 0; mm < 4; ++mm) {
            af[mm][0] = *(const bf16x8*)(sm + d * 32768 + mg * 16384 + (mm * 32 + ra) * 128 + swz0);
            af[mm][1] = *(const bf16x8*)(sm + d * 32768 + mg * 16384 + (mm * 32 + ra) * 128 + swz1);
        }
    };
    auto loadB = [&](int d, int ng, bf16x8 (&bfv)[2][2]) {
#pragma unroll
        for (int nn = 0; nn < 2; ++nn) {
            bfv[nn][0] = *(const bf16x8*)(sm + 65536 + d * 32768 + ng * 16384 + (nn * 64 + rb) * 128 + swz0);
            bfv[nn][1] = *(const bf16x8*)(sm + 65536 + d * 32768 + ng * 16384 + (nn * 64 + rb) * 128 + swz1);
        }
    };

    f32x4 acc[8][4] = {};

    // prologue: tile0 fully + 3 halves of tile1; drain tile0 (newest 6 in flight)
    stageA(0, 0, 0); stageB(0, 0, 0); stageB(0, 1, 0); stageA(0, 1, 0);
    stageA(1, 0, 1); stageB(1, 0, 1); stageB(1, 1, 1);
    asm volatile("s_waitcnt vmcnt(6)" ::: "memory");
    bar();

    const int NI = K / 128;
#pragma unroll 1
    for (int i = 0; i < NI; ++i) {
        const int t0 = 2 * i;
        const bool last = (i == NI - 1);
        // ---- P0: buf0, m-low x n-low ----
        loadA(0, 0); loadB(0, 0, bl);
        stageA(1, 1, t0 + 1);
        bar(); WAITL();
        __builtin_amdgcn_s_setprio(1); QUAD(0, 0, bl); __builtin_amdgcn_s_setprio(0);
        bar();
        // ---- P1 ----
        loadB(0, 1, bh);
        if (!last) stageA(0, 0, t0 + 2);
        bar(); WAITL();
        __builtin_amdgcn_s_setprio(1); QUAD(0, 1, bh); __builtin_amdgcn_s_setprio(0);
        bar();
        // ---- P2 ----
        loadA(0, 1);
        if (!last) stageB(0, 0, t0 + 2);
        bar(); WAITL();
        __builtin_amdgcn_s_setprio(1); QUAD(1, 0, bl); __builtin_amdgcn_s_setprio(0);
        bar();
        // ---- P3: gate buf1 (tile t0+1) ----
        if (!last) stageB(0, 1, t0 + 2);
        bar();
        __builtin_amdgcn_s_setprio(1); QUAD(1, 1, bh); __builtin_amdgcn_s_setprio(0);
        if (last) asm volatile("s_waitcnt vmcnt(0)" ::: "memory");
        else      asm volatile("s_waitcnt vmcnt(6)" ::: "memory");
        bar();
        // ---- P4: buf1, m-low x n-low ----
        loadA(1, 0); loadB(1, 0, bl);
        if (!last) stageA(0, 1, t0 + 2);
        bar(); WAITL();
        __builtin_amdgcn_s_setprio(1); QUAD(0, 0, bl); __builtin_amdgcn_s_setprio(0);
        bar();
        // ---- P5 ----
        loadB(1, 1, bh);
        if (!last) stageA(1, 0, t0 + 3);
        bar(); WAITL();
        __builtin_amdgcn_s_setprio(1); QUAD(0, 1, bh); __builtin_amdgcn_s_setprio(0);
        bar();
        // ---- P6 ----
        loadA(1, 1);
        if (!last) stageB(1, 0, t0 + 3);
        bar(); WAITL();
        __builtin_amdgcn_s_setprio(1); QUAD(1, 0, bl); __builtin_amdgcn_s_setprio(0);
        bar();
        // ---- P7: gate buf0 (tile t0+2) ----
        if (!last) stageB(1, 1, t0 + 3);
        bar();
        __builtin_amdgcn_s_setprio(1); QUAD(1, 1, bh); __builtin_amdgcn_s_setprio(0);
        if (!last) asm volatile("s_waitcnt vmcnt(6)" ::: "memory");
        bar();
    }

    const size_t row0 = (size_t)bm * 256 + wr * 16 + lrow * 4;
    if (MODE == 1) {
        const int col0 = bn * 256 + wc * 16 + lcol;
#pragma unroll
        for (int m = 0; m < 8; ++m)
#pragma unroll
            for (int n = 0; n < 4; ++n)
#pragma unroll
                for (int r = 0; r < 4; ++r)
                    ((float*)C)[(row0 + m * 32 + r) * N + col0 + n * 64] = acc[m][n][r];
    } else {
        const int seg = (bn * 256) >> 11;                       // which of Q/K/V
        const int coll = bn * 256 - seg * 2048 + wc * 16 + lcol;
        unsigned short* out = (unsigned short*)C + (size_t)seg * 16777216ull;
#pragma unroll
        for (int m = 0; m < 8; ++m)
#pragma unroll
            for (int n = 0; n < 4; ++n)
#pragma unroll
                for (int r = 0; r < 4; ++r)
                    out[(row0 + m * 32 + r) * 2048 + coll + n * 64] = f2bf(acc[m][n][r]);
    }
}

// ---------------- sliding-window attention (swapped ops, de-risked LDS) --------
__global__ __launch_bounds__(256, 3)
void swa_attn(const unsigned short* __restrict__ Qb, const unsigned short* __restrict__ Kb,
              const unsigned short* __restrict__ Vb, unsigned short* __restrict__ Ob) {
    constexpr int T = 4096, D = 2048;
    constexpr float SC = 0.18033688011112042f;   // log2(e)/8  (exp2 domain)

    __shared__ unsigned short vt[64][136];       // V^T chunk: [d][kt]
    __shared__ unsigned short pls[4][32][40];    // per-wave P slice: [q][kt32]

    const int bid  = blockIdx.x;
    const int flat = (bid & 7) * 256 + (bid >> 3);   // XCD-contiguous i-ranges
    const int i = flat & 31, h = (flat >> 5) & 31, b = flat >> 10;

    const int tid = threadIdx.x, wid = tid >> 6, lane = tid & 63;
    const int lcol = lane & 15, lrow = lane >> 4;

    const unsigned short* qp = Qb + (size_t)b * T * D + h * 64;
    const unsigned short* kp = Kb + (size_t)b * T * D + h * 64;
    const unsigned short* vp = Vb + (size_t)b * T * D + h * 64;

    const int t0 = (i == 0) ? 1 : 0;

    // Q fragments (B-operand of QK^T), held in regs
    const int q0 = i * 128 + wid * 32;
    bf16x8 aq[2][2];
#pragma unroll
    for (int qg = 0; qg < 2; ++qg)
#pragma unroll
        for (int kf = 0; kf < 2; ++kf)
            aq[qg][kf] = *(const bf16x8*)(qp + (size_t)(q0 + qg * 16 + lcol) * D + kf * 32 + lrow * 8);

    f32x4 oacc[2][4] = {};
    float mrun[2] = {-1e30f, -1e30f}, lrun[2] = {0.f, 0.f};

#pragma unroll 1
    for (int t = t0; t < 2; ++t) {
        const int kt0 = (i - 1 + t) * 128;

        // ---- stage V^T (coalesced 16B reads, b16 scatter writes) ----
#pragma unroll
        for (int it = 0; it < 4; ++it) {
            int e = it * 2048 + tid * 8;
            int kr = e >> 6;
            int dc = e & 63;
            bf16x8 v = *(const bf16x8*)(vp + (size_t)(kt0 + kr) * D + dc);
#pragma unroll
            for (int j = 0; j < 8; ++j) vt[dc + j][kr] = (unsigned short)v[j];
        }

        // ---- S^T = mfma(K, Q): lane holds S[q = qg*16+lcol][kt = 16n+4lrow+r] ----
        f32x4 s[2][8];
#pragma unroll
        for (int n = 0; n < 8; ++n) {
            const unsigned short* krow = kp + (size_t)(kt0 + n * 16 + lcol) * D + lrow * 8;
            bf16x8 k0 = *(const bf16x8*)(krow);
            bf16x8 k1 = *(const bf16x8*)(krow + 32);
            f32x4 z = {0.f, 0.f, 0.f, 0.f};
            s[0][n] = MFMA16(k1, aq[0][1], MFMA16(k0, aq[0][0], z));
            s[1][n] = MFMA16(k1, aq[1][1], MFMA16(k0, aq[1][0], z));
        }

        // ---- mask + scale into exp2 domain ----
#pragma unroll
        for (int qg = 0; qg < 2; ++qg) {
            const int q = wid * 32 + qg * 16 + lcol;
#pragma unroll
            for (int n = 0; n < 8; ++n) {
                const int cb = t * 128 + n * 16 + lrow * 4 - q;
#pragma unroll
                for (int r = 0; r < 4; ++r)
                    s[qg][n][r] = ((unsigned)(cb + r) <= 128u) ? s[qg][n][r] * SC : -1e30f;
            }
        }

        // ---- online softmax (row stats across lanes {l, l^16, l^32}) ----
#pragma unroll
        for (int qg = 0; qg < 2; ++qg) {
            float cm = -1e30f;
#pragma unroll
            for (int n = 0; n < 8; ++n)
#pragma unroll
                for (int r = 0; r < 4; ++r) cm = fmaxf(cm, s[qg][n][r]);
            cm = fmaxf(cm, __shfl_xor(cm, 16));
            cm = fmaxf(cm, __shfl_xor(cm, 32));
            const float mn = fmaxf(mrun[qg], cm);
            const float sf = fexp2(mrun[qg] - mn);
            mrun[qg] = mn;
            float rs = 0.f;
#pragma unroll
            for (int n = 0; n < 8; ++n)
#pragma unroll
                for (int r = 0; r < 4; ++r) {
                    float p = fexp2(s[qg][n][r] - mn);
                    s[qg][n][r] = p;
                    rs += p;
                }
            rs += __shfl_xor(rs, 16);
            rs += __shfl_xor(rs, 32);
            lrun[qg] = lrun[qg] * sf + rs;
#pragma unroll
            for (int nf = 0; nf < 4; ++nf) oacc[qg][nf] *= sf;
        }

        __syncthreads();   // vt writes visible to all waves

        // ---- O^T += mfma(V^T, P^T), per 32-kt slice ----
#pragma unroll
        for (int ks = 0; ks < 4; ++ks) {
            CFENCE();
#pragma unroll
            for (int qg = 0; qg < 2; ++qg) {
                unsigned short* prow = &pls[wid][qg * 16 + lcol][0];
#pragma unroll
                for (int r = 0; r < 4; ++r) {
                    prow[4 * lrow + r]      = f2bf(s[qg][2 * ks][r]);
                    prow[16 + 4 * lrow + r] = f2bf(s[qg][2 * ks + 1][r]);
                }
            }
            CFENCE();
            WAITL();   // drain ds_writes before same-wave cross-lane reads
            bf16x8 pf0 = *(const bf16x8*)&pls[wid][lcol][lrow * 8];
            bf16x8 pf1 = *(const bf16x8*)&pls[wid][16 + lcol][lrow * 8];
#pragma unroll
            for (int nf = 0; nf < 4; ++nf) {
                bf16x8 av = *(const bf16x8*)&vt[nf * 16 + lcol][ks * 32 + lrow * 8];
                oacc[0][nf] = MFMA16(av, pf0, oacc[0][nf]);
                oacc[1][nf] = MFMA16(av, pf1, oacc[1][nf]);
            }
            CFENCE();
        }

        __syncthreads();   // PV reads done before next chunk restages vt
    }

    // ---- normalize + store: lane owns q = lcol, d = 16nf + 4lrow + r ----
#pragma unroll
    for (int qg = 0; qg < 2; ++qg) {
        const float inv = 1.f / lrun[qg];
        const int tok = i * 128 + wid * 32 + qg * 16 + lcol;
        unsigned short* orow = Ob + (size_t)(b * T + tok) * D + h * 64;
#pragma unroll
        for (int nf = 0; nf < 4; ++nf) {
            unsigned o0 = (unsigned)f2bf(oacc[qg][nf][0] * inv) |
                          ((unsigned)f2bf(oacc[qg][nf][1] * inv) << 16);
            unsigned o1 = (unsigned)f2bf(oacc[qg][nf][2] * inv) |
                          ((unsigned)f2bf(oacc[qg][nf][3] * inv) << 16);
            *(u32x2*)(orow + nf * 16 + lrow * 4) = (u32x2){o0, o1};
        }
    }
}

// ---------------- launch -------------------------------------------------------
extern "C" void kernel_launch(void* const* d_in, const int* in_sizes, int n_in,
                              void* d_out, int out_size, void* d_ws, size_t ws_size,
                              hipStream_t stream) {
    const float* x  = (const float*)d_in[0];
    const float* Wq = (const float*)d_in[1];
    const float* Wk = (const float*)d_in[2];
    const float* Wv = (const float*)d_in[3];
    const float* Wo = (const float*)d_in[4];

    constexpr int B = 2, T = 4096, D = 2048;
    constexpr int M = B * T;                    // 8192
    constexpr size_t XE = (size_t)M * D;
    constexpr size_t WE = (size_t)D * D;

    char* ws = (char*)d_ws;
    unsigned short* xb  = (unsigned short*)(ws);
    unsigned short* wqb = (unsigned short*)(ws + XE * 2);               // Wq,Wk,Wv,Wo contiguous
    unsigned short* qb  = (unsigned short*)(ws + XE * 2 + WE * 8);      // Q,K,V contiguous
    unsigned short* kb  = (unsigned short*)(ws + XE * 4 + WE * 8);
    unsigned short* vb  = (unsigned short*)(ws + XE * 6 + WE * 8);
    unsigned short* ab  = (unsigned short*)(ws + XE * 8 + WE * 8);

    // single fused conversion: x + Wq + Wk + Wv + Wo -> contiguous bf16 region
    cvt_all<<<2048, 256, 0, stream>>>(x, Wq, Wk, Wv, Wo, xb, (int)((XE + 4 * WE) / 8));

    // fused QKV projection: C = x @ [Wq;Wk;Wv]^T, routed to qb/kb/vb
    gemm256<2><<<dim3((M / 256) * (6144 / 256)), 512, 0, stream>>>(xb, wqb, qb, M, 6144, D);

    swa_attn<<<dim3(2048), 256, 0, stream>>>(qb, kb, vb, ab);

    gemm256<1><<<dim3((M / 256) * (D / 256)), 512, 0, stream>>>(ab, wqb + 3 * WE, d_out, M, D, D);
}